// Round 6
// baseline (70.170 us; speedup 1.0000x reference)
//
#include <hip/hip_runtime.h>
#include <hip/hip_bf16.h>
#include <math.h>

// Problem constants (fixed by setup_inputs)
#define EDGES   32768
#define NPTS    32768
#define IMGH    256
#define L0      32768  // conv0 input length
#define L1      16384
#define L2      8192
#define L3      4096
// padded leading strides (+64 floats = +256 B) to break HBM channel camping
#define S0      (L1 + 64)   // Y0 row stride
#define S1      (L2 + 64)   // Y1 row stride

// ---------------------------------------------------------------------------
// Kernel 1 (fused prep): block-range dispatch, 648 x 512.
//   blocks   0..63  : edge lengths (f64) + in-block inclusive scan of 512
//   blocks  64..135 : weight transpose W[o][i][k] -> Wt[(i*3+k)*64+o] (x3)
//                     (+ block 64 t0 resets the convC ticket counter)
//   blocks 136..647 : image transpose (62,256,256) -> (65536,64), ch 62/63 = 0
// ---------------------------------------------------------------------------
__global__ __launch_bounds__(512) void prep_k(const float* __restrict__ corners,
                                              const float* __restrict__ W0,
                                              const float* __restrict__ W1,
                                              const float* __restrict__ W2,
                                              const float* __restrict__ img,
                                              double* __restrict__ el2loc,
                                              double* __restrict__ partial,
                                              float*  __restrict__ Wt,
                                              float*  __restrict__ imgT,
                                              unsigned* __restrict__ done)
{
    __shared__ union { double sc[512]; float tile[62][129]; } sm;
    int b = blockIdx.x, t = threadIdx.x;
    if (b < 64) {
        int e  = (b << 9) + t;
        int en = (e + 1) & (EDGES - 1);
        double dx = (double)corners[2*en]   - (double)corners[2*e];
        double dy = (double)corners[2*en+1] - (double)corners[2*e+1];
        sm.sc[t] = sqrt(dx*dx + dy*dy);
        __syncthreads();
        for (int o = 1; o < 512; o <<= 1) {        // Hillis-Steele inclusive
            double v = (t >= o) ? sm.sc[t - o] : 0.0;
            __syncthreads();
            sm.sc[t] += v;
            __syncthreads();
        }
        el2loc[e] = sm.sc[t];
        if (t == 511) partial[b] = sm.sc[511];
    } else if (b < 136) {
        if (b == 64 && t == 0) *done = 0u;         // reset convC ticket
        int idx = ((b - 64) << 9) + t;             // < 3*192*64 = 36864
        int l   = idx / 12288;
        int rem = idx - l * 12288;
        int row = rem >> 6, o = rem & 63;
        int i   = row / 3,  k = row - i * 3;
        const float* W = (l == 0) ? W0 : ((l == 1) ? W1 : W2);
        Wt[idx] = W[o*192 + i*3 + k];
    } else {
        int pix0 = (b - 136) << 7;                 // 128 pixels per block
        for (int idx = t; idx < 62*128; idx += 512) {
            int c = idx >> 7, p = idx & 127;
            sm.tile[c][p] = img[c * (IMGH*IMGH) + pix0 + p];
        }
        __syncthreads();
        for (int idx = t; idx < 128*64; idx += 512) {
            int p = idx >> 6, c = idx & 63;
            imgT[(size_t)(pix0 + p) * 64 + c] = (c < 62) ? sm.tile[c][p] : 0.f;
        }
    }
}

// ---------------------------------------------------------------------------
// Batched x-tile staging: 64 rows x 130 cols from Xin (reflect left halo),
// 32 fully-unrolled independent loads + 128-elem tail, THEN the LDS writes.
// LD = row stride of Xin (padded); Lin = logical length (reflect bound).
// ---------------------------------------------------------------------------
__device__ __forceinline__ void stage_xs(float xs[64][130],
                                         const float* __restrict__ Xin,
                                         int in0, int Lin, int LD, int tid)
{
    float r[32];
#pragma unroll
    for (int k = 0; k < 32; ++k) {
        int idx = k * 256 + tid;
        int i   = idx / 130;
        int pp  = idx - i * 130;
        int g   = in0 + pp;
        if (g < 0)    g = 1;
        if (g >= Lin) g = 2 * Lin - 2 - g;
        r[k] = Xin[i * LD + g];
    }
    float rt = 0.f;
    if (tid < 128) {                       // tail: idx 8192..8319 (row 63)
        int pp = 2 + tid;
        int g  = in0 + pp;
        if (g < 0)    g = 1;
        if (g >= Lin) g = 2 * Lin - 2 - g;
        rt = Xin[63 * LD + g];
    }
#pragma unroll
    for (int k = 0; k < 32; ++k) {
        int idx = k * 256 + tid;
        int i   = idx / 130;
        int pp  = idx - i * 130;
        xs[i][pp] = r[k];
    }
    if (tid < 128) xs[63][2 + tid] = rt;
}

// Batched weight-chunk staging: 96 rows x 64 ch = 1536 float4, 6 per thread.
__device__ __forceinline__ void stage_ws(float ws[96][64],
                                         const float* __restrict__ Wsrc,
                                         int tid)
{
    const float4* src = (const float4*)Wsrc;
    float4 rw[6];
#pragma unroll
    for (int k = 0; k < 6; ++k) rw[k] = src[k * 256 + tid];
    float4* dst = (float4*)&ws[0][0];
#pragma unroll
    for (int k = 0; k < 6; ++k) dst[k * 256 + tid] = rw[k];
}

// The 64x64 k=3 stride-2 conv compute on a staged half (32 input rows).
__device__ __forceinline__ void conv_half(float acc[16],
                                          const float xs[64][130],
                                          const float ws[96][64],
                                          int ibase, int jl2, int o0)
{
#pragma unroll 4
    for (int ii = 0; ii < 32; ++ii) {
        int i = ibase + ii;
        float x0 = xs[i][jl2], x1 = xs[i][jl2 + 1], x2 = xs[i][jl2 + 2];
        const float4* w0 = (const float4*)&ws[ii*3 + 0][o0];
        const float4* w1 = (const float4*)&ws[ii*3 + 1][o0];
        const float4* w2 = (const float4*)&ws[ii*3 + 2][o0];
#pragma unroll
        for (int q = 0; q < 4; ++q) {
            float4 a = w0[q], b = w1[q], c = w2[q];
            acc[q*4+0] = fmaf(a.x, x0, fmaf(b.x, x1, fmaf(c.x, x2, acc[q*4+0])));
            acc[q*4+1] = fmaf(a.y, x0, fmaf(b.y, x1, fmaf(c.y, x2, acc[q*4+1])));
            acc[q*4+2] = fmaf(a.z, x0, fmaf(b.z, x1, fmaf(c.z, x2, acc[q*4+2])));
            acc[q*4+3] = fmaf(a.w, x0, fmaf(b.w, x1, fmaf(c.w, x2, acc[q*4+3])));
        }
    }
}

// ---------------------------------------------------------------------------
// Kernel 2 (convA): fused point-gather + conv layer 0.  Writes Y0 (stride S0).
// ---------------------------------------------------------------------------
__global__ __launch_bounds__(256) void convA_k(const float* __restrict__ corners,
                                               const double* __restrict__ el2loc,
                                               const double* __restrict__ partial,
                                               const float* __restrict__ imgT,
                                               const float* __restrict__ Wt,
                                               const float* __restrict__ bias,
                                               float* __restrict__ Y0)
{
    __shared__ float  xs[64][130];   // 33280 B
    __shared__ float  ws[96][64];    // 24576 B
    __shared__ double sb[64];        //   512 B
    int tid = threadIdx.x;
    int j0  = blockIdx.x << 6;
    int in0 = (j0 << 1) - 1;

    // in-block scan of the 64 edge-chunk partials -> sb (inclusive)
    if (tid < 64) sb[tid] = partial[tid];
    __syncthreads();
#pragma unroll
    for (int o = 1; o < 64; o <<= 1) {
        double v = 0.0;
        if (tid < 64 && tid >= o) v = sb[tid - o];
        __syncthreads();
        if (tid < 64) sb[tid] += v;
        __syncthreads();
    }

    stage_ws(ws, Wt, tid);                 // chunk 0, batched, all threads

    if (tid < 130) {
        int g = in0 + tid;                 // point index for this column
        if (g < 0)   g = 1;                // reflect left
        if (g >= L0) g = 2*L0 - 2 - g;     // guard (halo, value unused)
        double S   = sb[63];
        double off = (double)g * (S * (1.0 / (double)NPTS));
        // two-level lower_bound: chunk via sb (LDS), then within 512 edges.
        int clo = 0, chi = 63;
        while (clo < chi) {
            int cm = (clo + chi) >> 1;
            if (sb[cm] > off) chi = cm; else clo = cm + 1;
        }
        double base = (clo == 0) ? 0.0 : sb[clo - 1];
        int lo = clo << 9, hi = lo + 511;
        while (lo < hi) {
            int mid = (lo + hi) >> 1;
            if (el2loc[mid] + base > off) hi = mid; else lo = mid + 1;
        }
        int e = lo;
        double e1 = (e == 0) ? 0.0
                  : el2loc[e-1] + (((e-1) >= 512) ? sb[((e-1) >> 9) - 1] : 0.0);
        float sxf = corners[2*e], syf = corners[2*e+1];
        int en = (e + 1) & (EDGES - 1);
        double dx = (double)corners[2*en]   - (double)sxf;
        double dy = (double)corners[2*en+1] - (double)syf;
        double len = sqrt(dx*dx + dy*dy);
        double t  = (off - e1) / fmax(len, 0.0001);
        double px = (double)sxf + t * dx;
        double py = (double)syf + t * dy;
        int r0 = (int)rint(px * (double)IMGH); r0 = r0 < 0 ? 0 : (r0 > IMGH-1 ? IMGH-1 : r0);
        int r1 = (int)rint(py * (double)IMGH); r1 = r1 < 0 ? 0 : (r1 > IMGH-1 ? IMGH-1 : r1);
        const float*  row  = imgT + (size_t)((r0 << 8) | r1) * 64;
        const float4* row4 = (const float4*)row;
        float4 rv[15];
#pragma unroll
        for (int c4 = 0; c4 < 15; ++c4) rv[c4] = row4[c4];   // batched loads
        float c60 = row[60], c61 = row[61];
#pragma unroll
        for (int c4 = 0; c4 < 15; ++c4) {
            xs[c4*4 + 0][tid] = rv[c4].x;
            xs[c4*4 + 1][tid] = rv[c4].y;
            xs[c4*4 + 2][tid] = rv[c4].z;
            xs[c4*4 + 3][tid] = rv[c4].w;
        }
        xs[60][tid] = c60;
        xs[61][tid] = c61;
        xs[62][tid] = (float)px;
        xs[63][tid] = (float)py;
    }
    __syncthreads();

    int lane = tid & 63;
    int o0   = (tid >> 6) << 4;
    float acc[16];
#pragma unroll
    for (int m = 0; m < 16; ++m) acc[m] = bias[o0 + m];
    int jl2 = lane << 1;

    conv_half(acc, xs, ws, 0, jl2, o0);
    __syncthreads();
    stage_ws(ws, Wt + 96*64, tid);         // chunk 1
    __syncthreads();
    conv_half(acc, xs, ws, 32, jl2, o0);

    int j = j0 + lane;
#pragma unroll
    for (int m = 0; m < 16; ++m)
        Y0[(o0 + m) * S0 + j] = fmaxf(acc[m], 0.f);
}

// ---------------------------------------------------------------------------
// Kernel 3 (convB): conv layer 1 (Y0 -> Y1), batched staging, padded strides.
// ---------------------------------------------------------------------------
__global__ __launch_bounds__(256) void convB_k(const float* __restrict__ Xin,
                                               const float* __restrict__ Wt,
                                               const float* __restrict__ bias,
                                               float* __restrict__ Yout)
{
    __shared__ float xs[64][130];
    __shared__ float ws[96][64];
    int tid = threadIdx.x;
    int j0  = blockIdx.x << 6;
    int in0 = (j0 << 1) - 1;

    stage_xs(xs, Xin, in0, L1, S0, tid);
    stage_ws(ws, Wt, tid);
    __syncthreads();

    int lane = tid & 63;
    int o0   = (tid >> 6) << 4;
    float acc[16];
#pragma unroll
    for (int m = 0; m < 16; ++m) acc[m] = bias[o0 + m];
    int jl2 = lane << 1;

    conv_half(acc, xs, ws, 0, jl2, o0);
    __syncthreads();
    stage_ws(ws, Wt + 96*64, tid);
    __syncthreads();
    conv_half(acc, xs, ws, 32, jl2, o0);

    int j = j0 + lane;
#pragma unroll
    for (int m = 0; m < 16; ++m)
        Yout[(o0 + m) * S1 + j] = fmaxf(acc[m], 0.f);
}

// ---------------------------------------------------------------------------
// Kernel 4 (convC): conv layer 2 + per-block channel max -> pmax; the LAST
// block to finish (ticket counter) reduces pmax and runs the two FCs.
// ---------------------------------------------------------------------------
__global__ __launch_bounds__(256) void convC_k(const float* __restrict__ Xin,
                                               const float* __restrict__ Wt,
                                               const float* __restrict__ bias,
                                               const float* __restrict__ Wf,
                                               const float* __restrict__ bf,
                                               const float* __restrict__ Wp,
                                               const float* __restrict__ bp,
                                               float* __restrict__ pmax,
                                               unsigned* __restrict__ done,
                                               float* __restrict__ out)
{
    __shared__ float xs[64][130];
    __shared__ float ws[96][64];
    __shared__ float cm[64];
    __shared__ float ft[64];
    __shared__ unsigned ticket;
    int tid = threadIdx.x;
    int j0  = blockIdx.x << 6;
    int in0 = (j0 << 1) - 1;

    stage_xs(xs, Xin, in0, L2, S1, tid);
    stage_ws(ws, Wt, tid);
    __syncthreads();

    int lane = tid & 63;
    int o0   = (tid >> 6) << 4;
    float acc[16];
#pragma unroll
    for (int m = 0; m < 16; ++m) acc[m] = bias[o0 + m];
    int jl2 = lane << 1;

    conv_half(acc, xs, ws, 0, jl2, o0);
    __syncthreads();
    stage_ws(ws, Wt + 96*64, tid);
    __syncthreads();
    conv_half(acc, xs, ws, 32, jl2, o0);

    // per-block channel max -> pmax[block*64 + ch]
#pragma unroll
    for (int m = 0; m < 16; ++m) {
        float v = fmaxf(acc[m], 0.f);
#pragma unroll
        for (int off = 1; off < 64; off <<= 1)
            v = fmaxf(v, __shfl_xor(v, off));
        if (lane == 0) pmax[blockIdx.x * 64 + o0 + m] = v;
    }
    __threadfence();
    __syncthreads();
    if (tid == 0) ticket = atomicAdd(done, 1u);
    __syncthreads();
    if (ticket == 63) {                  // last block: channel max + FCs
        __threadfence();
        if (tid < 64) {
            float m = 0.f;               // relu outputs >= 0
#pragma unroll
            for (int b = 0; b < 64; ++b) m = fmaxf(m, pmax[b * 64 + tid]);
            cm[tid] = m;
        }
        __syncthreads();
        if (tid < 64) {
            float s = bf[tid];
#pragma unroll
            for (int c = 0; c < 64; ++c) s = fmaf(Wf[tid*64 + c], cm[c], s);
            float f = fmaxf(s, 0.f);
            ft[tid] = f;
            out[tid] = f;
        }
        __syncthreads();
        if (tid == 0) {
            float z = bp[0];
#pragma unroll
            for (int c = 0; c < 64; ++c) z = fmaf(Wp[c], ft[c], z);
            out[64] = 1.f / (1.f + expf(-z));
        }
    }
}

// ---------------------------------------------------------------------------
extern "C" void kernel_launch(void* const* d_in, const int* in_sizes, int n_in,
                              void* d_out, int out_size, void* d_ws, size_t ws_size,
                              hipStream_t stream)
{
    const float* image   = (const float*)d_in[0];
    const float* corners = (const float*)d_in[1];
    const float* W0      = (const float*)d_in[2];
    const float* b0      = (const float*)d_in[3];
    const float* W1      = (const float*)d_in[4];
    const float* b1      = (const float*)d_in[5];
    const float* W2      = (const float*)d_in[6];
    const float* b2      = (const float*)d_in[7];
    const float* Wf      = (const float*)d_in[8];
    const float* bf      = (const float*)d_in[9];
    const float* Wp      = (const float*)d_in[10];
    const float* bp      = (const float*)d_in[11];
    float* out = (float*)d_out;

    // workspace layout (256B-aligned); d_ws is 256 MiB, we use ~23.6 MB
    char* w = (char*)d_ws;
    double*   el2loc  = (double*)  (w);              //   262144 B
    double*   partial = (double*)  (w + 262144);     //      512 B
    unsigned* done    = (unsigned*)(w + 262656);     //      256 B
    float*    pmax    = (float*)   (w + 262912);     //    16384 B
    float*    Wt      = (float*)   (w + 279296);     //   147456 B
    float*    imgT    = (float*)   (w + 426752);     // 16777216 B
    float*    Y0      = (float*)   (w + 17203968);   // 64*S0*4 = 4210688 B
    float*    Y1      = (float*)   (w + 21414656);   // 64*S1*4 = 2113536 B -> 23528192

    prep_k  <<<648, 512, 0, stream>>>(corners, W0, W1, W2, image,
                                      el2loc, partial, Wt, imgT, done);
    convA_k <<<L1 / 64, 256, 0, stream>>>(corners, el2loc, partial, imgT,
                                          Wt, b0, Y0);
    convB_k <<<L2 / 64, 256, 0, stream>>>(Y0, Wt + 12288, b1, Y1);
    convC_k <<<L3 / 64, 256, 0, stream>>>(Y1, Wt + 24576, b2,
                                          Wf, bf, Wp, bp, pmax, done, out);
}

// Round 7
// 54.719 us; speedup vs baseline: 1.2824x; 1.2824x over previous
//
#include <hip/hip_runtime.h>
#include <hip/hip_bf16.h>
#include <math.h>

// Problem constants (fixed by setup_inputs)
#define EDGES   32768
#define NPTS    32768
#define IMGH    256
#define L0      32768  // conv0 input length
#define L1      16384
#define L2      8192
#define L3      4096
#define S0      (L1 + 64)   // Y0 row stride (padded, harmless)
#define B2      31          // final outputs per convBC block
#define NBC     133         // ceil(4096/31)

// ---------------------------------------------------------------------------
// Kernel 1 (fused prep): block-range dispatch, 648 x 512.
//   blocks   0..63  : edge lengths (f64) + in-block inclusive scan of 512
//   blocks  64..135 : weight transpose W[o][i][k] -> Wt[(i*3+k)*64+o] (x3)
//   blocks 136..647 : image transpose (62,256,256) -> (65536,64), ch 62/63 = 0
// ---------------------------------------------------------------------------
__global__ __launch_bounds__(512) void prep_k(const float* __restrict__ corners,
                                              const float* __restrict__ W0,
                                              const float* __restrict__ W1,
                                              const float* __restrict__ W2,
                                              const float* __restrict__ img,
                                              double* __restrict__ el2loc,
                                              double* __restrict__ partial,
                                              float*  __restrict__ Wt,
                                              float*  __restrict__ imgT)
{
    __shared__ union { double sc[512]; float tile[62][129]; } sm;
    int b = blockIdx.x, t = threadIdx.x;
    if (b < 64) {
        int e  = (b << 9) + t;
        int en = (e + 1) & (EDGES - 1);
        double dx = (double)corners[2*en]   - (double)corners[2*e];
        double dy = (double)corners[2*en+1] - (double)corners[2*e+1];
        sm.sc[t] = sqrt(dx*dx + dy*dy);
        __syncthreads();
        for (int o = 1; o < 512; o <<= 1) {        // Hillis-Steele inclusive
            double v = (t >= o) ? sm.sc[t - o] : 0.0;
            __syncthreads();
            sm.sc[t] += v;
            __syncthreads();
        }
        el2loc[e] = sm.sc[t];
        if (t == 511) partial[b] = sm.sc[511];
    } else if (b < 136) {
        int idx = ((b - 64) << 9) + t;             // < 3*192*64 = 36864
        int l   = idx / 12288;
        int rem = idx - l * 12288;
        int row = rem >> 6, o = rem & 63;
        int i   = row / 3,  k = row - i * 3;
        const float* W = (l == 0) ? W0 : ((l == 1) ? W1 : W2);
        Wt[idx] = W[o*192 + i*3 + k];
    } else {
        int pix0 = (b - 136) << 7;                 // 128 pixels per block
        for (int idx = t; idx < 62*128; idx += 512) {
            int c = idx >> 7, p = idx & 127;
            sm.tile[c][p] = img[c * (IMGH*IMGH) + pix0 + p];
        }
        __syncthreads();
        for (int idx = t; idx < 128*64; idx += 512) {
            int p = idx >> 6, c = idx & 63;
            imgT[(size_t)(pix0 + p) * 64 + c] = (c < 62) ? sm.tile[c][p] : 0.f;
        }
    }
}

// Batched weight-chunk staging: 96 rows x 64 ch = 1536 float4, 6 per thread.
__device__ __forceinline__ void stage_ws(float ws[96][64],
                                         const float* __restrict__ Wsrc,
                                         int tid)
{
    const float4* src = (const float4*)Wsrc;
    float4 rw[6];
#pragma unroll
    for (int k = 0; k < 6; ++k) rw[k] = src[k * 256 + tid];
    float4* dst = (float4*)&ws[0][0];
#pragma unroll
    for (int k = 0; k < 6; ++k) dst[k * 256 + tid] = rw[k];
}

// 64x64 k=3 stride-2 conv compute on a staged half (convA only).
__device__ __forceinline__ void conv_half(float acc[16],
                                          const float xs[64][130],
                                          const float ws[96][64],
                                          int ibase, int jl2, int o0)
{
#pragma unroll 4
    for (int ii = 0; ii < 32; ++ii) {
        int i = ibase + ii;
        float x0 = xs[i][jl2], x1 = xs[i][jl2 + 1], x2 = xs[i][jl2 + 2];
        const float4* w0 = (const float4*)&ws[ii*3 + 0][o0];
        const float4* w1 = (const float4*)&ws[ii*3 + 1][o0];
        const float4* w2 = (const float4*)&ws[ii*3 + 2][o0];
#pragma unroll
        for (int q = 0; q < 4; ++q) {
            float4 a = w0[q], b = w1[q], c = w2[q];
            acc[q*4+0] = fmaf(a.x, x0, fmaf(b.x, x1, fmaf(c.x, x2, acc[q*4+0])));
            acc[q*4+1] = fmaf(a.y, x0, fmaf(b.y, x1, fmaf(c.y, x2, acc[q*4+1])));
            acc[q*4+2] = fmaf(a.z, x0, fmaf(b.z, x1, fmaf(c.z, x2, acc[q*4+2])));
            acc[q*4+3] = fmaf(a.w, x0, fmaf(b.w, x1, fmaf(c.w, x2, acc[q*4+3])));
        }
    }
}

// ---------------------------------------------------------------------------
// Kernel 2 (convA): fused point-gather + conv layer 0.  Writes Y0 (stride S0).
// ---------------------------------------------------------------------------
__global__ __launch_bounds__(256) void convA_k(const float* __restrict__ corners,
                                               const double* __restrict__ el2loc,
                                               const double* __restrict__ partial,
                                               const float* __restrict__ imgT,
                                               const float* __restrict__ Wt,
                                               const float* __restrict__ bias,
                                               float* __restrict__ Y0)
{
    __shared__ float  xs[64][130];   // 33280 B
    __shared__ float  ws[96][64];    // 24576 B
    __shared__ double sb[64];        //   512 B
    int tid = threadIdx.x;
    int j0  = blockIdx.x << 6;
    int in0 = (j0 << 1) - 1;

    // in-block scan of the 64 edge-chunk partials -> sb (inclusive)
    if (tid < 64) sb[tid] = partial[tid];
    __syncthreads();
#pragma unroll
    for (int o = 1; o < 64; o <<= 1) {
        double v = 0.0;
        if (tid < 64 && tid >= o) v = sb[tid - o];
        __syncthreads();
        if (tid < 64) sb[tid] += v;
        __syncthreads();
    }

    stage_ws(ws, Wt, tid);                 // chunk 0, batched, all threads

    if (tid < 130) {
        int g = in0 + tid;                 // point index for this column
        if (g < 0)   g = 1;                // reflect left
        if (g >= L0) g = 2*L0 - 2 - g;     // guard (halo, value unused)
        double S   = sb[63];
        double off = (double)g * (S * (1.0 / (double)NPTS));
        // two-level lower_bound: chunk via sb (LDS), then within 512 edges.
        int clo = 0, chi = 63;
        while (clo < chi) {
            int cm = (clo + chi) >> 1;
            if (sb[cm] > off) chi = cm; else clo = cm + 1;
        }
        double base = (clo == 0) ? 0.0 : sb[clo - 1];
        int lo = clo << 9, hi = lo + 511;
        while (lo < hi) {
            int mid = (lo + hi) >> 1;
            if (el2loc[mid] + base > off) hi = mid; else lo = mid + 1;
        }
        int e = lo;
        double e1 = (e == 0) ? 0.0
                  : el2loc[e-1] + (((e-1) >= 512) ? sb[((e-1) >> 9) - 1] : 0.0);
        float sxf = corners[2*e], syf = corners[2*e+1];
        int en = (e + 1) & (EDGES - 1);
        double dx = (double)corners[2*en]   - (double)sxf;
        double dy = (double)corners[2*en+1] - (double)syf;
        double len = sqrt(dx*dx + dy*dy);
        double t  = (off - e1) / fmax(len, 0.0001);
        double px = (double)sxf + t * dx;
        double py = (double)syf + t * dy;
        int r0 = (int)rint(px * (double)IMGH); r0 = r0 < 0 ? 0 : (r0 > IMGH-1 ? IMGH-1 : r0);
        int r1 = (int)rint(py * (double)IMGH); r1 = r1 < 0 ? 0 : (r1 > IMGH-1 ? IMGH-1 : r1);
        const float*  row  = imgT + (size_t)((r0 << 8) | r1) * 64;
        const float4* row4 = (const float4*)row;
        float4 rv[15];
#pragma unroll
        for (int c4 = 0; c4 < 15; ++c4) rv[c4] = row4[c4];   // batched loads
        float c60 = row[60], c61 = row[61];
#pragma unroll
        for (int c4 = 0; c4 < 15; ++c4) {
            xs[c4*4 + 0][tid] = rv[c4].x;
            xs[c4*4 + 1][tid] = rv[c4].y;
            xs[c4*4 + 2][tid] = rv[c4].z;
            xs[c4*4 + 3][tid] = rv[c4].w;
        }
        xs[60][tid] = c60;
        xs[61][tid] = c61;
        xs[62][tid] = (float)px;
        xs[63][tid] = (float)py;
    }
    __syncthreads();

    int lane = tid & 63;
    int o0   = (tid >> 6) << 4;
    float acc[16];
#pragma unroll
    for (int m = 0; m < 16; ++m) acc[m] = bias[o0 + m];
    int jl2 = lane << 1;

    conv_half(acc, xs, ws, 0, jl2, o0);
    __syncthreads();
    stage_ws(ws, Wt + 96*64, tid);         // chunk 1
    __syncthreads();
    conv_half(acc, xs, ws, 32, jl2, o0);

    int j = j0 + lane;
#pragma unroll
    for (int m = 0; m < 16; ++m)
        Y0[(o0 + m) * S0 + j] = fmaxf(acc[m], 0.f);
}

// ---------------------------------------------------------------------------
// Kernel 3 (convBC): conv1 + conv2 fused; Y1 never materialized.
// Block b owns final outputs j2 in [31b, 31b+31).
//   conv1 tile: 63 slots, j1 = 62b-1+s (reflect/clamp), from Y0 tile
//               [124b-3, 124b+125) staged in 2 in-channel halves [32][128].
//   conv2     : from t1[64][63] in LDS, 2 in-channel halves.
// Plain pmax stores; no atomics/fences. fc_k runs separately.
// ---------------------------------------------------------------------------
__global__ __launch_bounds__(256) void convBC_k(const float* __restrict__ Y0,
                                                const float* __restrict__ Wt1,
                                                const float* __restrict__ b1,
                                                const float* __restrict__ Wt2,
                                                const float* __restrict__ b2,
                                                float* __restrict__ pmax)
{
    __shared__ float xs0[32][132];   // 16896 B (staged Y0 half, cols 0..127 used)
    __shared__ float t1[64][63];     // 16128 B (conv1 output, relu'd)
    __shared__ float ws[96][64];     // 24576 B (weight chunk)
    int tid = threadIdx.x;
    int b   = blockIdx.x;
    int gbase = 124*b - 3;           // Y0 global col of xs0[.][0]

    // ---- conv1 lane geometry (computed once) ----
    int s  = tid & 63;                               // conv1 slot (63 used)
    int o0 = (tid >> 6) << 4;                        // 16-ch group
    int j1 = 62*b - 1 + s;
    int jr = (j1 < 0) ? -j1 : (j1 > L2-1 ? L2-1 : j1);   // reflect/clamp
    int col0 = 2*jr - 124*b + 2;                     // local col of Y0 idx 2jr-1

    // ---- stage Y0 half-0 (in-ch 0..31) + W1 chunk0, batched ----
    {
        float r[16];
#pragma unroll
        for (int k = 0; k < 16; ++k) {
            int idx = k*256 + tid;
            int c   = idx >> 7;                      // 0..31
            int col = idx & 127;
            int g   = gbase + col;
            if (g < 0)   g = -g;                     // reflect left (depth<=3)
            if (g >= L1) g = 2*L1 - 2 - g;           // reflect right
            r[k] = Y0[c * S0 + g];
        }
        stage_ws(ws, Wt1, tid);
#pragma unroll
        for (int k = 0; k < 16; ++k) {
            int idx = k*256 + tid;
            xs0[idx >> 7][idx & 127] = r[k];
        }
    }
    __syncthreads();

    float acc1[16];
#pragma unroll
    for (int m = 0; m < 16; ++m) acc1[m] = b1[o0 + m];

#pragma unroll 4
    for (int ii = 0; ii < 32; ++ii) {
        float x0 = xs0[ii][col0], x1 = xs0[ii][col0+1], x2 = xs0[ii][col0+2];
        const float4* w0 = (const float4*)&ws[ii*3 + 0][o0];
        const float4* w1 = (const float4*)&ws[ii*3 + 1][o0];
        const float4* w2 = (const float4*)&ws[ii*3 + 2][o0];
#pragma unroll
        for (int q = 0; q < 4; ++q) {
            float4 a = w0[q], bb = w1[q], c = w2[q];
            acc1[q*4+0] = fmaf(a.x, x0, fmaf(bb.x, x1, fmaf(c.x, x2, acc1[q*4+0])));
            acc1[q*4+1] = fmaf(a.y, x0, fmaf(bb.y, x1, fmaf(c.y, x2, acc1[q*4+1])));
            acc1[q*4+2] = fmaf(a.z, x0, fmaf(bb.z, x1, fmaf(c.z, x2, acc1[q*4+2])));
            acc1[q*4+3] = fmaf(a.w, x0, fmaf(bb.w, x1, fmaf(c.w, x2, acc1[q*4+3])));
        }
    }
    __syncthreads();

    // ---- stage Y0 half-1 (in-ch 32..63) + W1 chunk1 ----
    {
        float r[16];
#pragma unroll
        for (int k = 0; k < 16; ++k) {
            int idx = k*256 + tid;
            int c   = idx >> 7;
            int col = idx & 127;
            int g   = gbase + col;
            if (g < 0)   g = -g;
            if (g >= L1) g = 2*L1 - 2 - g;
            r[k] = Y0[(32 + c) * S0 + g];
        }
        stage_ws(ws, Wt1 + 96*64, tid);
#pragma unroll
        for (int k = 0; k < 16; ++k) {
            int idx = k*256 + tid;
            xs0[idx >> 7][idx & 127] = r[k];
        }
    }
    __syncthreads();

#pragma unroll 4
    for (int ii = 0; ii < 32; ++ii) {
        float x0 = xs0[ii][col0], x1 = xs0[ii][col0+1], x2 = xs0[ii][col0+2];
        const float4* w0 = (const float4*)&ws[ii*3 + 0][o0];
        const float4* w1 = (const float4*)&ws[ii*3 + 1][o0];
        const float4* w2 = (const float4*)&ws[ii*3 + 2][o0];
#pragma unroll
        for (int q = 0; q < 4; ++q) {
            float4 a = w0[q], bb = w1[q], c = w2[q];
            acc1[q*4+0] = fmaf(a.x, x0, fmaf(bb.x, x1, fmaf(c.x, x2, acc1[q*4+0])));
            acc1[q*4+1] = fmaf(a.y, x0, fmaf(bb.y, x1, fmaf(c.y, x2, acc1[q*4+1])));
            acc1[q*4+2] = fmaf(a.z, x0, fmaf(bb.z, x1, fmaf(c.z, x2, acc1[q*4+2])));
            acc1[q*4+3] = fmaf(a.w, x0, fmaf(bb.w, x1, fmaf(c.w, x2, acc1[q*4+3])));
        }
    }
    __syncthreads();                     // t1 region free (never aliased), xs0 done

    if (s < 63) {
#pragma unroll
        for (int m = 0; m < 16; ++m) t1[o0 + m][s] = fmaxf(acc1[m], 0.f);
    }
    __syncthreads();

    // ---- conv2: thread -> (pos p, 8-ch group) ----
    int p  = tid & 31;                   // 31 used
    int oc = (tid >> 5) << 3;
    float acc2[8];
#pragma unroll
    for (int q = 0; q < 8; ++q) acc2[q] = b2[oc + q];

    stage_ws(ws, Wt2, tid);              // W2 chunk0 (in-ch 0..31)
    __syncthreads();
#pragma unroll 4
    for (int ii = 0; ii < 32; ++ii) {
        float x0 = t1[ii][2*p + 0], x1 = t1[ii][2*p + 1], x2 = t1[ii][2*p + 2];
        const float4* w0 = (const float4*)&ws[ii*3 + 0][oc];
        const float4* w1 = (const float4*)&ws[ii*3 + 1][oc];
        const float4* w2 = (const float4*)&ws[ii*3 + 2][oc];
#pragma unroll
        for (int q4 = 0; q4 < 2; ++q4) {
            float4 a = w0[q4], bb = w1[q4], c = w2[q4];
            acc2[q4*4+0] = fmaf(a.x, x0, fmaf(bb.x, x1, fmaf(c.x, x2, acc2[q4*4+0])));
            acc2[q4*4+1] = fmaf(a.y, x0, fmaf(bb.y, x1, fmaf(c.y, x2, acc2[q4*4+1])));
            acc2[q4*4+2] = fmaf(a.z, x0, fmaf(bb.z, x1, fmaf(c.z, x2, acc2[q4*4+2])));
            acc2[q4*4+3] = fmaf(a.w, x0, fmaf(bb.w, x1, fmaf(c.w, x2, acc2[q4*4+3])));
        }
    }
    __syncthreads();
    stage_ws(ws, Wt2 + 96*64, tid);      // W2 chunk1 (in-ch 32..63)
    __syncthreads();
#pragma unroll 4
    for (int ii = 0; ii < 32; ++ii) {
        float x0 = t1[32+ii][2*p + 0], x1 = t1[32+ii][2*p + 1], x2 = t1[32+ii][2*p + 2];
        const float4* w0 = (const float4*)&ws[ii*3 + 0][oc];
        const float4* w1 = (const float4*)&ws[ii*3 + 1][oc];
        const float4* w2 = (const float4*)&ws[ii*3 + 2][oc];
#pragma unroll
        for (int q4 = 0; q4 < 2; ++q4) {
            float4 a = w0[q4], bb = w1[q4], c = w2[q4];
            acc2[q4*4+0] = fmaf(a.x, x0, fmaf(bb.x, x1, fmaf(c.x, x2, acc2[q4*4+0])));
            acc2[q4*4+1] = fmaf(a.y, x0, fmaf(bb.y, x1, fmaf(c.y, x2, acc2[q4*4+1])));
            acc2[q4*4+2] = fmaf(a.z, x0, fmaf(bb.z, x1, fmaf(c.z, x2, acc2[q4*4+2])));
            acc2[q4*4+3] = fmaf(a.w, x0, fmaf(bb.w, x1, fmaf(c.w, x2, acc2[q4*4+3])));
        }
    }

    // per-block channel max over the 31 valid positions, plain stores
    bool valid = (p < 31) && (31*b + p < L3);
#pragma unroll
    for (int q = 0; q < 8; ++q) {
        float v = valid ? fmaxf(acc2[q], 0.f) : 0.f;
#pragma unroll
        for (int off = 1; off < 32; off <<= 1)
            v = fmaxf(v, __shfl_xor(v, off));
        if (p == 0) pmax[b * 64 + oc + q] = v;
    }
}

// ---------------------------------------------------------------------------
// Kernel 4: channel max over NBC block-partials, then the two FCs + sigmoid.
// ---------------------------------------------------------------------------
__global__ __launch_bounds__(64) void fc_k(const float* __restrict__ pmax,
                                           const float* __restrict__ Wf,
                                           const float* __restrict__ bf,
                                           const float* __restrict__ Wp,
                                           const float* __restrict__ bp,
                                           float* __restrict__ out)
{
    __shared__ float cm[64];
    __shared__ float ft[64];
    int t = threadIdx.x;
    float m = 0.f;                       // relu outputs are >= 0
#pragma unroll
    for (int b = 0; b < NBC; ++b) m = fmaxf(m, pmax[b * 64 + t]);
    cm[t] = m;
    __syncthreads();
    float s = bf[t];
#pragma unroll
    for (int c = 0; c < 64; ++c) s = fmaf(Wf[t*64 + c], cm[c], s);
    float f = fmaxf(s, 0.f);
    ft[t] = f;
    out[t] = f;
    __syncthreads();
    if (t == 0) {
        float z = bp[0];
#pragma unroll
        for (int c = 0; c < 64; ++c) z = fmaf(Wp[c], ft[c], z);
        out[64] = 1.f / (1.f + expf(-z));
    }
}

// ---------------------------------------------------------------------------
extern "C" void kernel_launch(void* const* d_in, const int* in_sizes, int n_in,
                              void* d_out, int out_size, void* d_ws, size_t ws_size,
                              hipStream_t stream)
{
    const float* image   = (const float*)d_in[0];
    const float* corners = (const float*)d_in[1];
    const float* W0      = (const float*)d_in[2];
    const float* b0      = (const float*)d_in[3];
    const float* W1      = (const float*)d_in[4];
    const float* b1      = (const float*)d_in[5];
    const float* W2      = (const float*)d_in[6];
    const float* b2      = (const float*)d_in[7];
    const float* Wf      = (const float*)d_in[8];
    const float* bf      = (const float*)d_in[9];
    const float* Wp      = (const float*)d_in[10];
    const float* bp      = (const float*)d_in[11];
    float* out = (float*)d_out;

    // workspace layout (256B-aligned)
    char* w = (char*)d_ws;
    double*   el2loc  = (double*)  (w);              //   262144 B
    double*   partial = (double*)  (w + 262144);     //      512 B
    float*    pmax    = (float*)   (w + 262656);     //  NBC*64*4 = 34048 B
    float*    Wt      = (float*)   (w + 296960);     //   147456 B
    float*    imgT    = (float*)   (w + 444416);     // 16777216 B
    float*    Y0      = (float*)   (w + 17221632);   // 64*S0*4 = 4210688 B

    prep_k   <<<648, 512, 0, stream>>>(corners, W0, W1, W2, image,
                                       el2loc, partial, Wt, imgT);
    convA_k  <<<L1 / 64, 256, 0, stream>>>(corners, el2loc, partial, imgT,
                                           Wt, b0, Y0);
    convBC_k <<<NBC, 256, 0, stream>>>(Y0, Wt + 12288, b1, Wt + 24576, b2, pmax);
    fc_k     <<<1, 64, 0, stream>>>(pmax, Wf, bf, Wp, bp, out);
}